// Round 2
// baseline (1001.340 us; speedup 1.0000x reference)
//
#include <hip/hip_runtime.h>

// MultiHeadSelfAttn decode: q (1,32,512) fp32, k/v (8192,32,512) fp32.
// out (1,32,512) fp32. N_HEAD=8, D_HEAD=64, SCALE=1/8, CLIP=10.
// score = 10*tanh(SCALE*q.k) in [-10,10] -> exp safe -> single-pass softmax.
//
// R2 layout: block = (batch b, j-split s); each wave reads a full 2 KiB
// contiguous (j,b) row of K and V (all 8 heads). Lane l owns
// (head n = l>>3, d-slice (l&7)*8..+7). Only 3 shfl_xor per row for the
// 8-lane dot reduce; every lane owns a distinct output slice -> no
// intra-wave acc reduction. Cuts issue-cycles/byte ~2x vs R1 and raises
// DRAM chunk contiguity 256B -> 2KiB.

#define BATCH     32
#define NH        8
#define DH        64
#define DMODEL    512        // floats per (j,b) row
#define KLEN      8192
#define SPLITS    64         // j-split: 2048 blocks total
#define ROWS_PB   (KLEN / SPLITS)   // 128 rows per block
#define SCALE_F   0.125f
#define CLIP_F    10.0f

__global__ __launch_bounds__(256) void attn_partial(
    const float* __restrict__ q, const float* __restrict__ k,
    const float* __restrict__ v, float* __restrict__ part_num,
    float* __restrict__ part_den)
{
    const int b    = blockIdx.x & (BATCH - 1);
    const int s    = blockIdx.x >> 5;
    const int tid  = threadIdx.x;
    const int w    = tid >> 6;            // wave 0..3
    const int lane = tid & 63;
    const int n    = lane >> 3;           // head 0..7
    const int dsl  = (lane & 7) * 8;      // d-slice start within head

    // q fragment for this lane's (head, d-slice), pre-scaled
    const float* qp = q + b * DMODEL + n * DH + dsl;
    float4 q0 = *(const float4*)(qp);
    float4 q1 = *(const float4*)(qp + 4);
    q0.x *= SCALE_F; q0.y *= SCALE_F; q0.z *= SCALE_F; q0.w *= SCALE_F;
    q1.x *= SCALE_F; q1.y *= SCALE_F; q1.z *= SCALE_F; q1.w *= SCALE_F;

    // start row for this wave; waves stride by 4 rows
    const size_t base = (size_t)(s * ROWS_PB + w) * (BATCH * DMODEL)
                      + b * DMODEL + n * DH + dsl;
    const float* kp = k + base;
    const float* vp = v + base;
    const size_t step = (size_t)4 * BATCH * DMODEL;   // 4 rows per block-iter

    float4 a0 = make_float4(0.f, 0.f, 0.f, 0.f);
    float4 a1 = make_float4(0.f, 0.f, 0.f, 0.f);
    float  den = 0.f;

    #pragma unroll 2
    for (int it = 0; it < ROWS_PB / 4; ++it) {
        const float4 k0 = *(const float4*)(kp);
        const float4 k1 = *(const float4*)(kp + 4);
        const float4 v0 = *(const float4*)(vp);
        const float4 v1 = *(const float4*)(vp + 4);
        kp += step; vp += step;

        float pd = k0.x * q0.x + k0.y * q0.y + k0.z * q0.z + k0.w * q0.w
                 + k1.x * q1.x + k1.y * q1.y + k1.z * q1.z + k1.w * q1.w;
        // reduce over the 8 lanes of this head group (masks 1,2,4)
        pd += __shfl_xor(pd, 1);
        pd += __shfl_xor(pd, 2);
        pd += __shfl_xor(pd, 4);

        const float e2 = __expf(2.f * pd);
        const float th = 1.f - 2.f / (e2 + 1.f);      // tanh, inf-safe
        const float wg = __expf(CLIP_F * th);         // exp(score), <= e^10

        a0.x += wg * v0.x; a0.y += wg * v0.y; a0.z += wg * v0.z; a0.w += wg * v0.w;
        a1.x += wg * v1.x; a1.y += wg * v1.y; a1.z += wg * v1.z; a1.w += wg * v1.w;
        den  += wg;
    }

    // cross-wave reduction via LDS (once per block)
    __shared__ float lacc[4][DMODEL];
    __shared__ float lden[4][NH];
    ((float4*)&lacc[w][lane * 8])[0] = a0;
    ((float4*)&lacc[w][lane * 8])[1] = a1;
    if ((lane & 7) == 0) lden[w][n] = den;
    __syncthreads();

    // 512 outputs, 256 threads -> 2 each
    #pragma unroll
    for (int r = 0; r < 2; ++r) {
        const int c = tid + r * 256;
        const float num = lacc[0][c] + lacc[1][c] + lacc[2][c] + lacc[3][c];
        part_num[(size_t)blockIdx.x * DMODEL + c] = num;
    }
    if (tid < NH) {
        part_den[blockIdx.x * NH + tid] =
            lden[0][tid] + lden[1][tid] + lden[2][tid] + lden[3][tid];
    }
}

__global__ __launch_bounds__(512) void attn_reduce(
    const float* __restrict__ part_num, const float* __restrict__ part_den,
    float* __restrict__ out)
{
    const int b = blockIdx.x;        // 0..31
    const int c = threadIdx.x;       // 0..511
    const int n = c >> 6;
    float num = 0.f, den = 0.f;
    #pragma unroll 8
    for (int s = 0; s < SPLITS; ++s) {
        const int slot = s * BATCH + b;
        num += part_num[(size_t)slot * DMODEL + c];
        den += part_den[slot * NH + n];
    }
    out[b * DMODEL + c] = num / den;
}

extern "C" void kernel_launch(void* const* d_in, const int* in_sizes, int n_in,
                              void* d_out, int out_size, void* d_ws, size_t ws_size,
                              hipStream_t stream)
{
    const float* q = (const float*)d_in[0];
    const float* k = (const float*)d_in[1];
    const float* v = (const float*)d_in[2];
    float* out = (float*)d_out;

    float* part_num = (float*)d_ws;                                  // 2048*512 fp32
    float* part_den = part_num + (size_t)SPLITS * BATCH * DMODEL;    // 2048*8 fp32

    attn_partial<<<dim3(SPLITS * BATCH), dim3(256), 0, stream>>>(
        q, k, v, part_num, part_den);
    attn_reduce<<<dim3(BATCH), dim3(512), 0, stream>>>(part_num, part_den, out);
}